// Round 1
// baseline (230.708 us; speedup 1.0000x reference)
//
#include <hip/hip_runtime.h>

// SMap3x3: per-pixel argmin over 9 key_query planes -> one-hot scatter of
// (x,y,z,r) into a [B,3,3,4,H,W] output. Pure streaming, HBM-bound.
//
// Case analysis of the reference (valid/bad mutually exclusive):
//   r<=0.5          : sel_w = none,  sel_w2 = 4 (center)
//   r>0.5 && z>0    : sel_w = argmin, sel_w2 = argmin
//   r>0.5 && z<=0   : sel_w = 4,     sel_w2 = 4
// out[b,k,0..2,hw] = (k==sel_w) ? {x,y,z} : 0
// out[b,k,3,hw]    = (k==sel_w2) ? r : 0

constexpr int H = 480;
constexpr int W = 640;
constexpr int HW = H * W;          // 307200, divisible by 4
constexpr int HW4 = HW / 4;        // 76800 float4 per plane
constexpr int B = 4;
constexpr int NT = B * HW4;        // 307200 threads

__global__ __launch_bounds__(256) void smap3x3_kernel(
    const float4* __restrict__ x,
    const float4* __restrict__ y,
    const float4* __restrict__ z,
    const float4* __restrict__ r,
    const float4* __restrict__ kq,
    float4* __restrict__ out)
{
    int tid = blockIdx.x * blockDim.x + threadIdx.x;
    if (tid >= NT) return;
    int b   = tid / HW4;
    int hw4 = tid - b * HW4;

    float4 xv = x[tid];
    float4 yv = y[tid];
    float4 zv = z[tid];
    float4 rv = r[tid];

    float xs[4] = {xv.x, xv.y, xv.z, xv.w};
    float ys[4] = {yv.x, yv.y, yv.z, yv.w};
    float zs[4] = {zv.x, zv.y, zv.z, zv.w};
    float rs[4] = {rv.x, rv.y, rv.z, rv.w};

    // argmin over 9 planes (first-occurrence tie-break => strict <)
    const float4* kqb = kq + (size_t)b * 9 * HW4 + hw4;
    float4 k0 = kqb[0];
    float best[4] = {k0.x, k0.y, k0.z, k0.w};
    int   idx[4]  = {0, 0, 0, 0};
#pragma unroll
    for (int k = 1; k < 9; ++k) {
        float4 kk = kqb[(size_t)k * HW4];
        float vals[4] = {kk.x, kk.y, kk.z, kk.w};
#pragma unroll
        for (int l = 0; l < 4; ++l) {
            if (vals[l] < best[l]) { best[l] = vals[l]; idx[l] = k; }
        }
    }

    int selw[4], selw2[4];
#pragma unroll
    for (int l = 0; l < 4; ++l) {
        bool ron = rs[l] > 0.5f;
        bool zon = zs[l] > 0.0f;
        selw[l]  = ron ? (zon ? idx[l] : 4) : -1;   // -1: no xz write
        selw2[l] = (ron && zon) ? idx[l] : 4;
    }

    float4* outb = out + (size_t)b * 36 * HW4 + hw4;
#pragma unroll
    for (int k = 0; k < 9; ++k) {
        float4 o0, o1, o2, o3;
        float* p0 = &o0.x; float* p1 = &o1.x; float* p2 = &o2.x; float* p3 = &o3.x;
#pragma unroll
        for (int l = 0; l < 4; ++l) {
            float wv  = (k == selw[l])  ? 1.0f : 0.0f;
            p0[l] = wv * xs[l];
            p1[l] = wv * ys[l];
            p2[l] = wv * zs[l];
            p3[l] = (k == selw2[l]) ? rs[l] : 0.0f;
        }
        outb[(size_t)(k * 4 + 0) * HW4] = o0;
        outb[(size_t)(k * 4 + 1) * HW4] = o1;
        outb[(size_t)(k * 4 + 2) * HW4] = o2;
        outb[(size_t)(k * 4 + 3) * HW4] = o3;
    }
}

extern "C" void kernel_launch(void* const* d_in, const int* in_sizes, int n_in,
                              void* d_out, int out_size, void* d_ws, size_t ws_size,
                              hipStream_t stream) {
    const float4* x  = (const float4*)d_in[0];
    const float4* y  = (const float4*)d_in[1];
    const float4* z  = (const float4*)d_in[2];
    const float4* r  = (const float4*)d_in[3];
    const float4* kq = (const float4*)d_in[4];
    float4* out = (float4*)d_out;

    constexpr int block = 256;
    constexpr int grid  = (NT + block - 1) / block;  // 1200
    smap3x3_kernel<<<grid, block, 0, stream>>>(x, y, z, r, kq, out);
}

// Round 2
// 230.292 us; speedup vs baseline: 1.0018x; 1.0018x over previous
//
#include <hip/hip_runtime.h>

// SMap3x3: per-pixel argmin over 9 key_query planes -> one-hot scatter of
// (x,y,z,r) into a [B,3,3,4,H,W] output. Pure streaming, HBM write-bound.
//
// Case analysis of the reference (valid/bad mutually exclusive):
//   r<=0.5          : sel_w = none (-1), sel_w2 = 4 (center)
//   r>0.5 && z>0    : sel_w = argmin,    sel_w2 = argmin
//   r>0.5 && z<=0   : sel_w = 4,         sel_w2 = 4
// out[b,k,0..2,hw] = (k==sel_w) ? {x,y,z} : 0
// out[b,k,3,hw]    = (k==sel_w2) ? r : 0
//
// R1 lesson: taking &float4.x and indexing across members demoted the output
// temporaries to scratch (private mem) -> ~5x slowdown. This version is fully
// scalar: no local arrays, no member-pointer arithmetic.

constexpr int H = 480;
constexpr int W = 640;
constexpr int HW = H * W;          // 307200
constexpr int HW4 = HW / 4;        // 76800 float4 per plane
constexpr int BLK = 256;
constexpr int GRIDX = HW4 / BLK;   // 300 (exact)

__global__ __launch_bounds__(256) void smap3x3_kernel(
    const float4* __restrict__ x,
    const float4* __restrict__ y,
    const float4* __restrict__ z,
    const float4* __restrict__ r,
    const float4* __restrict__ kq,
    float4* __restrict__ out)
{
    const int hw4 = blockIdx.x * BLK + threadIdx.x;  // [0, HW4)
    const int b   = blockIdx.y;                      // [0, 4)
    const size_t pix = (size_t)b * HW4 + hw4;

    const float4 xv = x[pix];
    const float4 yv = y[pix];
    const float4 zv = z[pix];
    const float4 rv = r[pix];

    // argmin over 9 planes, per component (first-occurrence tie-break: strict <)
    const float4* kqb = kq + (size_t)b * 9 * HW4 + hw4;
    float4 best = kqb[0];
    int i0 = 0, i1 = 0, i2 = 0, i3 = 0;
#pragma unroll
    for (int k = 1; k < 9; ++k) {
        const float4 kk = kqb[(size_t)k * HW4];
        if (kk.x < best.x) { best.x = kk.x; i0 = k; }
        if (kk.y < best.y) { best.y = kk.y; i1 = k; }
        if (kk.z < best.z) { best.z = kk.z; i2 = k; }
        if (kk.w < best.w) { best.w = kk.w; i3 = k; }
    }

    // per-component selectors
    int sw0, sw1, sw2, sw3;   // xyz plane selector (-1 = none)
    int s20, s21, s22, s23;   // r plane selector
    { const bool ron = rv.x > 0.5f, zon = zv.x > 0.0f;
      sw0 = ron ? (zon ? i0 : 4) : -1;  s20 = (ron && zon) ? i0 : 4; }
    { const bool ron = rv.y > 0.5f, zon = zv.y > 0.0f;
      sw1 = ron ? (zon ? i1 : 4) : -1;  s21 = (ron && zon) ? i1 : 4; }
    { const bool ron = rv.z > 0.5f, zon = zv.z > 0.0f;
      sw2 = ron ? (zon ? i2 : 4) : -1;  s22 = (ron && zon) ? i2 : 4; }
    { const bool ron = rv.w > 0.5f, zon = zv.w > 0.0f;
      sw3 = ron ? (zon ? i3 : 4) : -1;  s23 = (ron && zon) ? i3 : 4; }

    float4* outb = out + (size_t)b * 36 * HW4 + hw4;
#pragma unroll
    for (int k = 0; k < 9; ++k) {
        float4 ox, oy, oz, orr;
        const bool m0 = (k == sw0), m1 = (k == sw1), m2 = (k == sw2), m3 = (k == sw3);
        ox.x = m0 ? xv.x : 0.0f;  ox.y = m1 ? xv.y : 0.0f;
        ox.z = m2 ? xv.z : 0.0f;  ox.w = m3 ? xv.w : 0.0f;
        oy.x = m0 ? yv.x : 0.0f;  oy.y = m1 ? yv.y : 0.0f;
        oy.z = m2 ? yv.z : 0.0f;  oy.w = m3 ? yv.w : 0.0f;
        oz.x = m0 ? zv.x : 0.0f;  oz.y = m1 ? zv.y : 0.0f;
        oz.z = m2 ? zv.z : 0.0f;  oz.w = m3 ? zv.w : 0.0f;
        orr.x = (k == s20) ? rv.x : 0.0f;  orr.y = (k == s21) ? rv.y : 0.0f;
        orr.z = (k == s22) ? rv.z : 0.0f;  orr.w = (k == s23) ? rv.w : 0.0f;

        outb[(size_t)(4 * k + 0) * HW4] = ox;
        outb[(size_t)(4 * k + 1) * HW4] = oy;
        outb[(size_t)(4 * k + 2) * HW4] = oz;
        outb[(size_t)(4 * k + 3) * HW4] = orr;
    }
}

extern "C" void kernel_launch(void* const* d_in, const int* in_sizes, int n_in,
                              void* d_out, int out_size, void* d_ws, size_t ws_size,
                              hipStream_t stream) {
    const float4* x  = (const float4*)d_in[0];
    const float4* y  = (const float4*)d_in[1];
    const float4* z  = (const float4*)d_in[2];
    const float4* r  = (const float4*)d_in[3];
    const float4* kq = (const float4*)d_in[4];
    float4* out = (float4*)d_out;

    dim3 grid(GRIDX, 4);  // 300 x 4 blocks, exact cover
    smap3x3_kernel<<<grid, dim3(BLK), 0, stream>>>(x, y, z, r, kq, out);
}

// Round 4
// 224.843 us; speedup vs baseline: 1.0261x; 1.0242x over previous
//
#include <hip/hip_runtime.h>

// SMap3x3: per-pixel argmin over 9 key_query planes -> one-hot scatter of
// (x,y,z,r) into a [B,3,3,4,H,W] output. Pure streaming, HBM write-bound.
//
// Case analysis of the reference (valid/bad mutually exclusive):
//   r<=0.5          : sel_w = none (-1), sel_w2 = 4 (center)
//   r>0.5 && z>0    : sel_w = argmin,    sel_w2 = argmin
//   r>0.5 && z<=0   : sel_w = 4,         sel_w2 = 4
// out[b,k,0..2,hw] = (k==sel_w) ? {x,y,z} : 0
// out[b,k,3,hw]    = (k==sel_w2) ? r : 0
//
// R3 fix: __builtin_nontemporal_* requires a native vector type, not
// HIP_vector_type. Use ext_vector_type(4) float for all NT accesses.

constexpr int H = 480;
constexpr int W = 640;
constexpr int HW = H * W;          // 307200
constexpr int HW4 = HW / 4;        // 76800 float4 per plane
constexpr int BLK = 256;
constexpr int GRIDX = HW4 / BLK;   // 300 (exact)

typedef __attribute__((ext_vector_type(4))) float fvec4;

__device__ __forceinline__ fvec4 nt_load4(const fvec4* p) {
    return __builtin_nontemporal_load(p);
}
__device__ __forceinline__ void nt_store4(fvec4* p, fvec4 v) {
    __builtin_nontemporal_store(v, p);
}

__global__ __launch_bounds__(256) void smap3x3_kernel(
    const fvec4* __restrict__ x,
    const fvec4* __restrict__ y,
    const fvec4* __restrict__ z,
    const fvec4* __restrict__ r,
    const fvec4* __restrict__ kq,
    fvec4* __restrict__ out)
{
    const int hw4 = blockIdx.x * BLK + threadIdx.x;  // [0, HW4)
    const int b   = blockIdx.y;                      // [0, 4)
    const size_t pix = (size_t)b * HW4 + hw4;

    const fvec4 xv = nt_load4(x + pix);
    const fvec4 yv = nt_load4(y + pix);
    const fvec4 zv = nt_load4(z + pix);
    const fvec4 rv = nt_load4(r + pix);

    // argmin over 9 planes, per component (first-occurrence tie-break: strict <)
    const fvec4* kqb = kq + (size_t)b * 9 * HW4 + hw4;
    fvec4 best = nt_load4(kqb);
    int i0 = 0, i1 = 0, i2 = 0, i3 = 0;
#pragma unroll
    for (int k = 1; k < 9; ++k) {
        const fvec4 kk = nt_load4(kqb + (size_t)k * HW4);
        if (kk.x < best.x) { best.x = kk.x; i0 = k; }
        if (kk.y < best.y) { best.y = kk.y; i1 = k; }
        if (kk.z < best.z) { best.z = kk.z; i2 = k; }
        if (kk.w < best.w) { best.w = kk.w; i3 = k; }
    }

    // per-component selectors
    int sw0, sw1, sw2, sw3;   // xyz plane selector (-1 = none)
    int s20, s21, s22, s23;   // r plane selector
    { const bool ron = rv.x > 0.5f, zon = zv.x > 0.0f;
      sw0 = ron ? (zon ? i0 : 4) : -1;  s20 = (ron && zon) ? i0 : 4; }
    { const bool ron = rv.y > 0.5f, zon = zv.y > 0.0f;
      sw1 = ron ? (zon ? i1 : 4) : -1;  s21 = (ron && zon) ? i1 : 4; }
    { const bool ron = rv.z > 0.5f, zon = zv.z > 0.0f;
      sw2 = ron ? (zon ? i2 : 4) : -1;  s22 = (ron && zon) ? i2 : 4; }
    { const bool ron = rv.w > 0.5f, zon = zv.w > 0.0f;
      sw3 = ron ? (zon ? i3 : 4) : -1;  s23 = (ron && zon) ? i3 : 4; }

    fvec4* outb = out + (size_t)b * 36 * HW4 + hw4;
#pragma unroll
    for (int k = 0; k < 9; ++k) {
        fvec4 ox, oy, oz, orr;
        const bool m0 = (k == sw0), m1 = (k == sw1), m2 = (k == sw2), m3 = (k == sw3);
        ox.x = m0 ? xv.x : 0.0f;  ox.y = m1 ? xv.y : 0.0f;
        ox.z = m2 ? xv.z : 0.0f;  ox.w = m3 ? xv.w : 0.0f;
        oy.x = m0 ? yv.x : 0.0f;  oy.y = m1 ? yv.y : 0.0f;
        oy.z = m2 ? yv.z : 0.0f;  oy.w = m3 ? yv.w : 0.0f;
        oz.x = m0 ? zv.x : 0.0f;  oz.y = m1 ? zv.y : 0.0f;
        oz.z = m2 ? zv.z : 0.0f;  oz.w = m3 ? zv.w : 0.0f;
        orr.x = (k == s20) ? rv.x : 0.0f;  orr.y = (k == s21) ? rv.y : 0.0f;
        orr.z = (k == s22) ? rv.z : 0.0f;  orr.w = (k == s23) ? rv.w : 0.0f;

        nt_store4(outb + (size_t)(4 * k + 0) * HW4, ox);
        nt_store4(outb + (size_t)(4 * k + 1) * HW4, oy);
        nt_store4(outb + (size_t)(4 * k + 2) * HW4, oz);
        nt_store4(outb + (size_t)(4 * k + 3) * HW4, orr);
    }
}

extern "C" void kernel_launch(void* const* d_in, const int* in_sizes, int n_in,
                              void* d_out, int out_size, void* d_ws, size_t ws_size,
                              hipStream_t stream) {
    const fvec4* x  = (const fvec4*)d_in[0];
    const fvec4* y  = (const fvec4*)d_in[1];
    const fvec4* z  = (const fvec4*)d_in[2];
    const fvec4* r  = (const fvec4*)d_in[3];
    const fvec4* kq = (const fvec4*)d_in[4];
    fvec4* out = (fvec4*)d_out;

    dim3 grid(GRIDX, 4);  // 300 x 4 blocks, exact cover
    smap3x3_kernel<<<grid, dim3(BLK), 0, stream>>>(x, y, z, r, kq, out);
}